// Round 11
// baseline (80.196 us; speedup 1.0000x reference)
//
#include <hip/hip_runtime.h>
#include <cfloat>
#include <cstdint>

#define BB 4
#define NN 8192

typedef short bf16x8 __attribute__((ext_vector_type(8)));
typedef float f32x4  __attribute__((ext_vector_type(4)));

// ws layout (bytes):
//   [0, 256K)        rowpart float[2][BB][NN]  (pass0 = dist1 mins, pass1 = dist2 mins)
//   [256K, 256K+4M)  images 1MB each: A_gt, A_pred, B_pred, B_gt  (32 B / point)
//   [PART_OFF, ...)  partial[64] f32
#define ROW_OFF  0
#define IMG_OFF  262144
#define PART_OFF (262144 + 4*1048576)

static __device__ __forceinline__ float vmin2(float a, float b) {
    float r;
    asm("v_min_f32 %0, %1, %2" : "=v"(r) : "v"(a), "v"(b));
    return r;
}
__device__ __forceinline__ unsigned short btr(float v) {       // truncate to bf16
    return (unsigned short)(__float_as_uint(v) >> 16);
}
__device__ __forceinline__ float bup(unsigned short h) {
    return __uint_as_float(((unsigned)h) << 16);
}
__device__ __forceinline__ unsigned pk2(unsigned short a, unsigned short b) {
    return (unsigned)a | ((unsigned)b << 16);
}

// Per-point 32B records, 16 bf16 slots (k-groups 0,1 of the 16x16x32 MFMA).
// Slot pairing A[s]*B[s]:
//  g0: uh.x*vh.x uh.y*vh.y uh.z*vh.z ul.x*vh.x ul.y*vh.y ul.z*vh.z sqA_h*1 sqA_m*1
//  g1: uh.x*vl.x uh.y*vl.y uh.z*vl.z 1*sqB_h 1*sqB_m 1*sqB_l sqA_l*1 0*0
// Sum = u.v + |p_row|^2 + |p_col|^2 - ul.vl   (u = -2*row-point)  = d(r,c) + O(2^-16)
__global__ __launch_bounds__(256) void chamfer_prep_kernel(
    const float* __restrict__ pred, const float* __restrict__ gt,
    const float* __restrict__ coords, char* __restrict__ wsb)
{
    const int t = blockIdx.x * 256 + threadIdx.x;   // 65536 threads
    const int cloud = t >> 15;                      // 0 = gt, 1 = pred
    const int i = t & 32767;                        // b*NN + n
    const float* reg = cloud ? pred : gt;
    const size_t base = (size_t)(i >> 13) * 3 * NN + (i & (NN - 1));
    float x = coords[base]          + reg[base];
    float y = coords[base + NN]     + reg[base + NN];
    float z = coords[base + 2*NN]   + reg[base + 2*NN];
    float sq = fmaf(x, x, fmaf(y, y, z * z));
    // v splits (B role)
    unsigned short vhx = btr(x), vhy = btr(y), vhz = btr(z);
    unsigned short vlx = btr(x - bup(vhx)), vly = btr(y - bup(vhy)), vlz = btr(z - bup(vhz));
    // sq 3-way split (shared by A and B roles)
    unsigned short sh = btr(sq); float sr = sq - bup(sh);
    unsigned short sm = btr(sr); unsigned short sl = btr(sr - bup(sm));
    // u = -2*point splits (A role)
    float ux = -2.f * x, uy = -2.f * y, uz = -2.f * z;
    unsigned short uhx = btr(ux), uhy = btr(uy), uhz = btr(uz);
    unsigned short ulx = btr(ux - bup(uhx)), uly = btr(uy - bup(uhy)), ulz = btr(uz - bup(uhz));
    const unsigned short ONE = 0x3F80;
    uint4 Ag0 = make_uint4(pk2(uhx, uhy), pk2(uhz, ulx), pk2(uly, ulz), pk2(sh, sm));
    uint4 Ag1 = make_uint4(pk2(uhx, uhy), pk2(uhz, ONE), pk2(ONE, ONE), pk2(sl, 0));
    uint4 Bg0 = make_uint4(pk2(vhx, vhy), pk2(vhz, vhx), pk2(vhy, vhz), pk2(ONE, ONE));
    uint4 Bg1 = make_uint4(pk2(vlx, vly), pk2(vlz, sh), pk2(sm, sl), pk2(ONE, 0));
    uint4* Aimg = (uint4*)(wsb + IMG_OFF + (size_t)cloud * 1048576);
    uint4* Bimg = (uint4*)(wsb + IMG_OFF + 2097152 + (size_t)(1 - cloud) * 1048576);
    Aimg[(size_t)i * 2]     = Ag0;  Aimg[(size_t)i * 2 + 1] = Ag1;
    Bimg[(size_t)i * 2]     = Bg0;  Bimg[(size_t)i * 2 + 1] = Bg1;
}

// Pass p (z): rows = cloud p, cols = other cloud. Block: 4 waves x 32 rows =
// 128 rows, sweeps all 8192 cols in 8 LDS-staged chunks of 1024 (dbuf 2x32KB,
// register-staged T14-style). Row mins in regs; plain stores (no atomics).
// D layout (m89-verified): col = lane&15, row = (lane>>4)*4 + reg.
__global__ __launch_bounds__(256) void chamfer_mfma_kernel(char* __restrict__ wsb)
{
    const int p = blockIdx.z, b = blockIdx.y, rg = blockIdx.x;
    const int tid = threadIdx.x, w = tid >> 6, l = tid & 63;
    const int lg = l >> 4, lr = l & 15;
    const bool valid = lg < 2;                 // k-groups 2,3 are zero
    const uint4* Aimg = (const uint4*)(wsb + IMG_OFF + (size_t)p * 1048576);
    const uint4* Bimg = (const uint4*)(wsb + IMG_OFF + 2097152 + (size_t)p * 1048576);
    __shared__ uint4 sB[2][2048];              // 2 x 32 KB chunks

    const int rbase = rg * 128 + w * 32;
    bf16x8 a0 = {}, a1 = {};
    if (valid) {
        a0 = *(const bf16x8*)(Aimg + (size_t)(b * NN + rbase + lr) * 2 + lg);
        a1 = *(const bf16x8*)(Aimg + (size_t)(b * NN + rbase + 16 + lr) * 2 + lg);
    }
    float r0[4], r1[4];
    #pragma unroll
    for (int j = 0; j < 4; ++j) { r0[j] = FLT_MAX; r1[j] = FLT_MAX; }
    const f32x4 z4 = {0.f, 0.f, 0.f, 0.f};

    const uint4* Bb = Bimg + (size_t)b * NN * 2;   // 16384 uint4 per batch
    uint4* s4 = &sB[0][0];
    uint4 st[8];
    #pragma unroll
    for (int i = 0; i < 8; ++i) st[i] = Bb[i * 256 + tid];   // chunk 0
    #pragma unroll
    for (int i = 0; i < 8; ++i) s4[i * 256 + tid] = st[i];
    __syncthreads();

    for (int c = 0; c < 8; ++c) {
        if (c < 7) {                           // issue next chunk's loads early
            #pragma unroll
            for (int i = 0; i < 8; ++i) st[i] = Bb[(c + 1) * 2048 + i * 256 + tid];
        }
        const uint4* cur = s4 + (c & 1) * 2048;
        bf16x8 bf = {};
        if (valid) bf = *(const bf16x8*)(cur + lr * 2 + lg);
        #pragma unroll 4
        for (int s = 0; s < 64; ++s) {
            bf16x8 bn = {};
            if (valid && s < 63)
                bn = *(const bf16x8*)(cur + ((s + 1) * 16 + lr) * 2 + lg);
            f32x4 d0 = __builtin_amdgcn_mfma_f32_16x16x32_bf16(a0, bf, z4, 0, 0, 0);
            f32x4 d1 = __builtin_amdgcn_mfma_f32_16x16x32_bf16(a1, bf, z4, 0, 0, 0);
            #pragma unroll
            for (int j = 0; j < 4; ++j) {
                r0[j] = vmin2(r0[j], d0[j]);
                r1[j] = vmin2(r1[j], d1[j]);
            }
            bf = bn;
        }
        __syncthreads();                       // all waves done reading cur
        if (c < 7) {                           // write prefetched chunk
            #pragma unroll
            for (int i = 0; i < 8; ++i) s4[((c + 1) & 1) * 2048 + i * 256 + tid] = st[i];
        }
        __syncthreads();                       // stage visible before next reads
    }

    // min over the 16 cols held by this 16-lane group
    #pragma unroll
    for (int j = 0; j < 4; ++j) {
        float v = r0[j];
        v = vmin2(v, __shfl_xor(v, 1)); v = vmin2(v, __shfl_xor(v, 2));
        v = vmin2(v, __shfl_xor(v, 4)); v = vmin2(v, __shfl_xor(v, 8));
        r0[j] = v;
        float u = r1[j];
        u = vmin2(u, __shfl_xor(u, 1)); u = vmin2(u, __shfl_xor(u, 2));
        u = vmin2(u, __shfl_xor(u, 4)); u = vmin2(u, __shfl_xor(u, 8));
        r1[j] = u;
    }
    if (lr == 0) {                             // lanes 0,16,32,48: rows lg*4+reg
        float* rowpart = (float*)(wsb + ROW_OFF);
        const size_t o = ((size_t)p * BB + b) * NN + rbase + lg * 4;
        #pragma unroll
        for (int j = 0; j < 4; ++j) {
            rowpart[o + j]      = r0[j];
            rowpart[o + 16 + j] = r1[j];
        }
    }
}

// stage A: 64 blocks x 256 threads, float4 per thread over 65536 row mins
__global__ __launch_bounds__(256) void chamfer_reduce_a(
    const float* __restrict__ rp, float* __restrict__ partial)
{
    int idx = blockIdx.x * 256 + threadIdx.x;
    float4 u = ((const float4*)rp)[idx];
    float s = (u.x + u.y) + (u.z + u.w);
    #pragma unroll
    for (int off = 32; off > 0; off >>= 1)
        s += __shfl_down(s, off);
    __shared__ float sm[4];
    if ((threadIdx.x & 63) == 0) sm[threadIdx.x >> 6] = s;
    __syncthreads();
    if (threadIdx.x == 0)
        partial[blockIdx.x] = (sm[0] + sm[1]) + (sm[2] + sm[3]);
}

__global__ __launch_bounds__(64) void chamfer_reduce_b(
    const float* __restrict__ partial, float* __restrict__ out)
{
    float s = partial[threadIdx.x];
    #pragma unroll
    for (int off = 32; off > 0; off >>= 1)
        s += __shfl_down(s, off);
    if (threadIdx.x == 0) out[0] = s * (1.0f / (float)BB);
}

extern "C" void kernel_launch(void* const* d_in, const int* in_sizes, int n_in,
                              void* d_out, int out_size, void* d_ws, size_t ws_size,
                              hipStream_t stream) {
    const float* pred   = (const float*)d_in[0];
    const float* gt     = (const float*)d_in[1];
    const float* coords = (const float*)d_in[2];
    char*  wsb  = (char*)d_ws;
    float* part = (float*)(wsb + PART_OFF);
    float* out  = (float*)d_out;

    chamfer_prep_kernel<<<256, 256, 0, stream>>>(pred, gt, coords, wsb);
    dim3 grid(64, BB, 2);                      // 64 rowgroups x 4 batches x 2 passes
    chamfer_mfma_kernel<<<grid, 256, 0, stream>>>(wsb);
    chamfer_reduce_a<<<64, 256, 0, stream>>>((const float*)wsb, part);
    chamfer_reduce_b<<<1, 64, 0, stream>>>(part, out);
}